// Round 3
// baseline (665.909 us; speedup 1.0000x reference)
//
#include <hip/hip_runtime.h>
#include <cstdint>
#include <cstddef>

typedef unsigned short u16;
typedef unsigned int u32;
typedef short bf16x8 __attribute__((ext_vector_type(8)));
typedef float f32x4 __attribute__((ext_vector_type(4)));

__device__ __forceinline__ float bf2f(u16 u){
  union { u32 i; float f; } c; c.i = ((u32)u) << 16; return c.f;
}
__device__ __forceinline__ u16 f2bf(float f){
  union { float f; u32 i; } c; c.f = f;
  u32 r = c.i + 0x7FFFu + ((c.i >> 16) & 1u);
  return (u16)(r >> 16);
}
__device__ __forceinline__ void gload_lds16(const void* g, void* l){
  __builtin_amdgcn_global_load_lds(
      (const __attribute__((address_space(1))) u32*)g,
      (__attribute__((address_space(3))) u32*)l, 16, 0, 0);
}

// ---------------- f32 -> bf16 conversion (inputs arrive as float32) --------
__global__ __launch_bounds__(256)
void f32_to_bf16(const float* __restrict__ src, u16* __restrict__ dst, int n8){
  int i = blockIdx.x * 256 + threadIdx.x;
  if (i >= n8) return;
  const float4* s = (const float4*)src + (size_t)i * 2;
  float4 a = s[0], b = s[1];
  u16 o[8] = {f2bf(a.x),f2bf(a.y),f2bf(a.z),f2bf(a.w),
              f2bf(b.x),f2bf(b.y),f2bf(b.z),f2bf(b.w)};
  *(uint4*)(dst + (size_t)i * 8) = *(const uint4*)o;
}

// ---------------- generic GEMM: C = epi(A @ W^T + bias) ----------------
// A: [M,K] bf16, W: [N,K] bf16. EPI: 0=bias (bf16 out), 1=silu (bf16 out),
// 2=final: I + w0*(acc+bias), f32 out (d_out is float32 per harness contract).
template<int EPI>
__global__ __launch_bounds__(256, 2)
void gemm_bt(const u16* __restrict__ A, const u16* __restrict__ W,
             const float* __restrict__ bias, void* __restrict__ Cv,
             int M, int N, int K,
             const u16* __restrict__ I, const float* __restrict__ sw)
{
  __shared__ __align__(16) u16 As[128*64];
  __shared__ __align__(16) u16 Bs[128*64];
  const int tid  = threadIdx.x;
  const int lane = tid & 63;
  const int wave = tid >> 6;
  const int wr = wave >> 1, wc = wave & 1;
  const int m0 = blockIdx.y * 128, n0 = blockIdx.x * 128;

  f32x4 acc[4][4];
  #pragma unroll
  for (int r=0;r<4;++r)
    #pragma unroll
    for (int c=0;c<4;++c)
      #pragma unroll
      for (int e=0;e<4;++e) acc[r][c][e] = 0.f;

  int srow[4], soff[4];
  #pragma unroll
  for (int j=0;j<4;++j){
    int rr = (wave*4 + j)*8 + (lane>>3);
    srow[j] = rr;
    soff[j] = ((lane & 7) ^ (rr & 7)) * 8;   // pre-swizzled global chunk
  }

  for (int k0 = 0; k0 < K; k0 += 64){
    #pragma unroll
    for (int j=0;j<4;++j){
      gload_lds16(A + (size_t)(m0 + srow[j])*K + k0 + soff[j], As + (wave*4+j)*512);
      gload_lds16(W + (size_t)(n0 + srow[j])*K + k0 + soff[j], Bs + (wave*4+j)*512);
    }
    __syncthreads();
    #pragma unroll
    for (int ks=0; ks<2; ++ks){
      bf16x8 af[4], bfr[4];
      #pragma unroll
      for (int r=0;r<4;++r){
        int row = wr*64 + r*16 + (lane&15);
        int cs  = (ks*4 + (lane>>4)) ^ (row & 7);
        af[r] = *(const bf16x8*)(As + row*64 + cs*8);
      }
      #pragma unroll
      for (int c=0;c<4;++c){
        int row = wc*64 + c*16 + (lane&15);
        int cs  = (ks*4 + (lane>>4)) ^ (row & 7);
        bfr[c] = *(const bf16x8*)(Bs + row*64 + cs*8);
      }
      #pragma unroll
      for (int r=0;r<4;++r)
        #pragma unroll
        for (int c=0;c<4;++c)
          acc[r][c] = __builtin_amdgcn_mfma_f32_16x16x32_bf16(af[r], bfr[c], acc[r][c], 0,0,0);
    }
    __syncthreads();
  }

  float w0 = 0.f;
  if (EPI == 2){
    float s0 = sw[0], s1 = sw[1], s2 = sw[2];
    float mx = fmaxf(s0, fmaxf(s1, s2));
    float e0 = __expf(s0-mx), e1 = __expf(s1-mx), e2 = __expf(s2-mx);
    w0 = e0 / (e0 + e1 + e2);
  }
  u16*   C16 = (u16*)Cv;
  float* C32 = (float*)Cv;
  #pragma unroll
  for (int c=0;c<4;++c){
    int col = n0 + wc*64 + c*16 + (lane&15);
    float bv = bias[col];
    #pragma unroll
    for (int r=0;r<4;++r){
      int rbase = m0 + wr*64 + r*16 + (lane>>4)*4;
      #pragma unroll
      for (int e=0;e<4;++e){
        int row = rbase + e;
        float v = acc[r][c][e] + bv;
        if (EPI == 1) v = v / (1.f + __expf(-v));
        if (EPI == 2){
          v = bf2f(I[(size_t)row*N + col]) + w0 * v;
          C32[(size_t)row*N + col] = v;
        } else {
          C16[(size_t)row*N + col] = f2bf(v);
        }
      }
    }
  }
}

// ---------------- LayerNorm (one wave per token) ----------------
// OUTF32: outp is float* (expert outputs); else bf16. MASK: route-mask + cat write.
template<int D, int MASK, int OUTF32>
__global__ __launch_bounds__(256, 4)
void ln_k(const u16* __restrict__ H, const float* __restrict__ g,
          const float* __restrict__ beta, const int* __restrict__ st,
          int eid, void* __restrict__ outp, u16* __restrict__ cat, int catOff)
{
  const int tid = threadIdx.x, lane = tid & 63, wave = tid >> 6;
  const int token = blockIdx.x * 4 + wave;
  constexpr int VPT = D / 64;
  float v[VPT];
  const u16* row = H + (size_t)token * D + lane * VPT;
  #pragma unroll
  for (int i=0;i<VPT/2;++i){
    u32 u = ((const u32*)row)[i];
    v[2*i]   = bf2f((u16)(u & 0xFFFFu));
    v[2*i+1] = bf2f((u16)(u >> 16));
  }
  float s = 0.f;
  #pragma unroll
  for (int i=0;i<VPT;++i) s += v[i];
  #pragma unroll
  for (int off=1; off<64; off<<=1) s += __shfl_xor(s, off);
  float mu = s * (1.f / D);
  float q = 0.f;
  #pragma unroll
  for (int i=0;i<VPT;++i){ float d = v[i] - mu; q += d * d; }
  #pragma unroll
  for (int off=1; off<64; off<<=1) q += __shfl_xor(q, off);
  float rs = rsqrtf(q * (1.f / D) + 1e-5f);
  float msk = 1.f;
  if (MASK) msk = (st[token] == eid) ? 1.f : 0.f;
  u16* crow = cat + (size_t)token * 896 + catOff + lane * VPT;
  #pragma unroll
  for (int i=0;i<VPT;++i){
    float gg = g[lane*VPT + i];
    float bb = beta[lane*VPT + i];
    float val = (gg * (v[i] - mu) * rs + bb) * msk;
    if (OUTF32) ((float*)outp)[(size_t)token * D + lane * VPT + i] = val;
    else        ((u16*)outp)[(size_t)token * D + lane * VPT + i] = f2bf(val);
    if (MASK) crow[i] = f2bf(val);
  }
}

// ---------------- flash attention (B=4,S=2048,H=8,Dh=128) ----------------
__global__ __launch_bounds__(256, 2)
void flash_attn(const u16* __restrict__ qkv, u16* __restrict__ o)
{
  __shared__ __align__(16) u16 Qs[64*136];
  __shared__ __align__(16) u16 Ks[64*136];
  __shared__ __align__(16) u16 Vt[128*72];
  __shared__ __align__(16) u16 Ps[4*16*72];
  const int tid = threadIdx.x, lane = tid & 63, wave = tid >> 6;
  const int b = blockIdx.z, h = blockIdx.y, q0 = blockIdx.x * 64;
  const float scale = 0.08838834764831845f;  // 1/sqrt(128)

  #pragma unroll
  for (int i=0;i<4;++i){
    int id = tid + 256*i;
    int r = id >> 4, c8 = id & 15;
    const uint4* gq = (const uint4*)(qkv + (size_t)(b*2048 + q0 + r)*3072 + h*128 + c8*8);
    *(uint4*)(Qs + r*136 + c8*8) = *gq;
  }

  f32x4 oacc[8];
  #pragma unroll
  for (int f=0;f<8;++f)
    #pragma unroll
    for (int e=0;e<4;++e) oacc[f][e] = 0.f;
  float m_run[4] = {-3e38f,-3e38f,-3e38f,-3e38f};
  float l_run[4] = {0.f,0.f,0.f,0.f};

  for (int kt=0; kt<32; ++kt){
    const int k0 = kt * 64;
    #pragma unroll
    for (int i=0;i<4;++i){
      int id = tid + 256*i;
      int r = id >> 4, c8 = id & 15;
      const size_t rb = (size_t)(b*2048 + k0 + r)*3072 + h*128;
      *(uint4*)(Ks + r*136 + c8*8) = *(const uint4*)(qkv + rb + 1024 + c8*8);
      uint4 tv = *(const uint4*)(qkv + rb + 2048 + c8*8);
      const u16* pv = (const u16*)&tv;
      #pragma unroll
      for (int j=0;j<8;++j) Vt[(c8*8 + j)*72 + r] = pv[j];
    }
    __syncthreads();

    f32x4 s[4];
    #pragma unroll
    for (int cb=0;cb<4;++cb)
      #pragma unroll
      for (int e=0;e<4;++e) s[cb][e] = 0.f;
    #pragma unroll
    for (int kk=0;kk<4;++kk){
      bf16x8 aq = *(const bf16x8*)(Qs + (wave*16 + (lane&15))*136 + kk*32 + (lane>>4)*8);
      #pragma unroll
      for (int cb=0;cb<4;++cb){
        bf16x8 bk = *(const bf16x8*)(Ks + ((lane&15) + 16*cb)*136 + kk*32 + (lane>>4)*8);
        s[cb] = __builtin_amdgcn_mfma_f32_16x16x32_bf16(aq, bk, s[cb], 0,0,0);
      }
    }

    u16* PsW = Ps + wave*16*72;
    #pragma unroll
    for (int e=0;e<4;++e){
      float t0 = s[0][e]*scale, t1 = s[1][e]*scale, t2 = s[2][e]*scale, t3 = s[3][e]*scale;
      float mx = fmaxf(fmaxf(t0,t1), fmaxf(t2,t3));
      #pragma unroll
      for (int off=1; off<16; off<<=1) mx = fmaxf(mx, __shfl_xor(mx, off));
      float mnew = fmaxf(m_run[e], mx);
      float a = __expf(m_run[e] - mnew);
      m_run[e] = mnew;
      float p0 = __expf(t0-mnew), p1 = __expf(t1-mnew), p2 = __expf(t2-mnew), p3 = __expf(t3-mnew);
      float rsum = p0+p1+p2+p3;
      #pragma unroll
      for (int off=1; off<16; off<<=1) rsum += __shfl_xor(rsum, off);
      l_run[e] = l_run[e]*a + rsum;
      #pragma unroll
      for (int f=0;f<8;++f) oacc[f][e] *= a;
      int prow = (lane>>4)*4 + e;
      PsW[prow*72 +  0 + (lane&15)] = f2bf(p0);
      PsW[prow*72 + 16 + (lane&15)] = f2bf(p1);
      PsW[prow*72 + 32 + (lane&15)] = f2bf(p2);
      PsW[prow*72 + 48 + (lane&15)] = f2bf(p3);
    }

    #pragma unroll
    for (int kk=0;kk<2;++kk){
      bf16x8 pa = *(const bf16x8*)(PsW + (lane&15)*72 + kk*32 + (lane>>4)*8);
      #pragma unroll
      for (int f=0;f<8;++f){
        bf16x8 vb = *(const bf16x8*)(Vt + ((lane&15) + 16*f)*72 + kk*32 + (lane>>4)*8);
        oacc[f] = __builtin_amdgcn_mfma_f32_16x16x32_bf16(pa, vb, oacc[f], 0,0,0);
      }
    }
    __syncthreads();
  }

  #pragma unroll
  for (int f=0;f<8;++f)
    #pragma unroll
    for (int e=0;e<4;++e){
      int row = q0 + wave*16 + (lane>>4)*4 + e;
      int col = h*128 + f*16 + (lane&15);
      o[(size_t)(b*2048 + row)*1024 + col] = f2bf(oacc[f][e] / l_run[e]);
    }
}

// ---------------- launch ----------------
extern "C" void kernel_launch(void* const* d_in, const int* in_sizes, int n_in,
                              void* d_out, int out_size, void* d_ws, size_t ws_size,
                              hipStream_t stream)
{
  const float* x         = (const float*)d_in[0];
  const int*   stypes    = (const int*)d_in[1];
  const float* mol_W1    = (const float*)d_in[2];
  const float* mol_b1    = (const float*)d_in[3];
  const float* mol_W2    = (const float*)d_in[4];
  const float* mol_b2    = (const float*)d_in[5];
  const float* mol_g     = (const float*)d_in[6];
  const float* mol_beta  = (const float*)d_in[7];
  const float* path_W1   = (const float*)d_in[8];
  const float* path_b1   = (const float*)d_in[9];
  const float* path_W2   = (const float*)d_in[10];
  const float* path_b2   = (const float*)d_in[11];
  const float* path_g    = (const float*)d_in[12];
  const float* path_beta = (const float*)d_in[13];
  const float* cell_W1   = (const float*)d_in[14];
  const float* cell_b1   = (const float*)d_in[15];
  const float* cell_W2   = (const float*)d_in[16];
  const float* cell_b2   = (const float*)d_in[17];
  const float* cell_g    = (const float*)d_in[18];
  const float* cell_beta = (const float*)d_in[19];
  const float* int_W1    = (const float*)d_in[20];
  const float* int_b1    = (const float*)d_in[21];
  const float* int_W2    = (const float*)d_in[22];
  const float* int_b2    = (const float*)d_in[23];
  const float* int_g     = (const float*)d_in[24];
  const float* int_beta  = (const float*)d_in[25];
  const float* attn_Wqkv = (const float*)d_in[26];
  const float* attn_bqkv = (const float*)d_in[27];
  const float* attn_Wo   = (const float*)d_in[28];
  const float* attn_bo   = (const float*)d_in[29];
  const float* scale_w   = (const float*)d_in[30];

  float* out_final = (float*)d_out;           // [8192,1024] f32
  float* out_mol   = out_final + 8388608;     // [8192,128]  f32
  float* out_path  = out_mol   + 1048576;     // [8192,256]  f32
  float* out_cell  = out_path  + 2097152;     // [8192,512]  f32

  u16* ws    = (u16*)d_ws;
  u16* qkv   = ws;                  // 8192*3072 (early: xb + cat)
  u16* integ = qkv   + 25165824;    // 8192*1024
  u16* S1    = integ + 8388608;     // 8192*1024 scratch
  u16* S2    = S1    + 8388608;     // 8192*1024 scratch
  u16* wb    = S2    + 8388608;     // bf16 weights
  u16* xb    = qkv;                 // [8192,1024] bf16 (dead before qkv GEMM)
  u16* cat   = qkv + 8388608;       // [8192,896] bf16 (dead before qkv GEMM)

  // bf16 weight copies
  u16* molW1b  = wb;                   // 131072
  u16* molW2b  = molW1b  + 131072;     // 16384
  u16* pathW1b = molW2b  + 16384;      // 262144
  u16* pathW2b = pathW1b + 262144;     // 65536
  u16* cellW1b = pathW2b + 65536;      // 524288
  u16* cellW2b = cellW1b + 524288;     // 262144
  u16* intW1b  = cellW2b + 262144;     // 917504
  u16* intW2b  = intW1b  + 917504;     // 1048576
  u16* qkvWb   = intW2b  + 1048576;    // 3145728
  u16* woWb    = qkvWb   + 3145728;    // 1048576

  dim3 blk(256);
  const int M = 8192;
  auto conv = [&](const float* s, u16* d, int n){
    int n8 = n / 8;
    f32_to_bf16<<<(n8 + 255)/256, blk, 0, stream>>>(s, d, n8);
  };

  conv(x,         xb,      8388608);
  conv(mol_W1,    molW1b,  131072);
  conv(mol_W2,    molW2b,  16384);
  conv(path_W1,   pathW1b, 262144);
  conv(path_W2,   pathW2b, 65536);
  conv(cell_W1,   cellW1b, 524288);
  conv(cell_W2,   cellW2b, 262144);
  conv(int_W1,    intW1b,  917504);
  conv(int_W2,    intW2b,  1048576);
  conv(attn_Wqkv, qkvWb,   3145728);
  conv(attn_Wo,   woWb,    1048576);

  // experts (dense over all tokens; masked at LN)
  gemm_bt<1><<<dim3(1,64), blk, 0, stream>>>(xb, molW1b, mol_b1, S1, M, 128, 1024, nullptr, nullptr);
  gemm_bt<0><<<dim3(1,64), blk, 0, stream>>>(S1, molW2b, mol_b2, S2, M, 128, 128,  nullptr, nullptr);
  ln_k<128,1,1><<<2048, blk, 0, stream>>>(S2, mol_g, mol_beta, stypes, 0, out_mol, cat, 0);

  gemm_bt<1><<<dim3(2,64), blk, 0, stream>>>(xb, pathW1b, path_b1, S1, M, 256, 1024, nullptr, nullptr);
  gemm_bt<0><<<dim3(2,64), blk, 0, stream>>>(S1, pathW2b, path_b2, S2, M, 256, 256,  nullptr, nullptr);
  ln_k<256,1,1><<<2048, blk, 0, stream>>>(S2, path_g, path_beta, stypes, 1, out_path, cat, 128);

  gemm_bt<1><<<dim3(4,64), blk, 0, stream>>>(xb, cellW1b, cell_b1, S1, M, 512, 1024, nullptr, nullptr);
  gemm_bt<0><<<dim3(4,64), blk, 0, stream>>>(S1, cellW2b, cell_b2, S2, M, 512, 512,  nullptr, nullptr);
  ln_k<512,1,1><<<2048, blk, 0, stream>>>(S2, cell_g, cell_beta, stypes, 2, out_cell, cat, 384);

  // integration
  gemm_bt<1><<<dim3(8,64), blk, 0, stream>>>(cat, intW1b, int_b1, S1, M, 1024, 896,  nullptr, nullptr);
  gemm_bt<0><<<dim3(8,64), blk, 0, stream>>>(S1,  intW2b, int_b2, S2, M, 1024, 1024, nullptr, nullptr);
  ln_k<1024,0,0><<<2048, blk, 0, stream>>>(S2, int_g, int_beta, nullptr, 0, integ, integ, 0);

  // attention (xb/cat dead from here; qkv region reused)
  gemm_bt<0><<<dim3(24,64), blk, 0, stream>>>(integ, qkvWb, attn_bqkv, qkv, M, 3072, 1024, nullptr, nullptr);
  flash_attn<<<dim3(32,8,4), blk, 0, stream>>>(qkv, S1);

  // final = integ + w0*(o @ Wo^T + bo), f32 out
  gemm_bt<2><<<dim3(8,64), blk, 0, stream>>>(S1, woWb, attn_bo, out_final, M, 1024, 1024, integ, scale_w);
}

// Round 4
// 580.947 us; speedup vs baseline: 1.1462x; 1.1462x over previous
//
#include <hip/hip_runtime.h>
#include <cstdint>
#include <cstddef>

typedef unsigned short u16;
typedef unsigned int u32;
typedef short bf16x8 __attribute__((ext_vector_type(8)));
typedef float f32x4 __attribute__((ext_vector_type(4)));

__device__ __forceinline__ float bf2f(u16 u){
  union { u32 i; float f; } c; c.i = ((u32)u) << 16; return c.f;
}
__device__ __forceinline__ u16 f2bf(float f){
  union { float f; u32 i; } c; c.f = f;
  u32 r = c.i + 0x7FFFu + ((c.i >> 16) & 1u);
  return (u16)(r >> 16);
}
__device__ __forceinline__ void gload_lds16(const void* g, void* l){
  __builtin_amdgcn_global_load_lds(
      (const __attribute__((address_space(1))) u32*)g,
      (__attribute__((address_space(3))) u32*)l, 16, 0, 0);
}

// ---------------- f32 -> bf16 conversion (inputs arrive as float32) --------
__global__ __launch_bounds__(256)
void f32_to_bf16(const float* __restrict__ src, u16* __restrict__ dst, int n8){
  int i = blockIdx.x * 256 + threadIdx.x;
  if (i >= n8) return;
  const float4* s = (const float4*)src + (size_t)i * 2;
  float4 a = s[0], b = s[1];
  u16 o[8] = {f2bf(a.x),f2bf(a.y),f2bf(a.z),f2bf(a.w),
              f2bf(b.x),f2bf(b.y),f2bf(b.z),f2bf(b.w)};
  *(uint4*)(dst + (size_t)i * 8) = *(const uint4*)o;
}

// ---------------- generic GEMM: C = epi(A @ W^T + bias) ----------------
// A: [M,K] bf16, W: [N,K] bf16. EPI: 0=bias (bf16 out), 1=silu (bf16 out),
// 2=final: I + w0*(acc+bias), f32 out.
template<int EPI>
__global__ __launch_bounds__(256, 2)
void gemm_bt(const u16* __restrict__ A, const u16* __restrict__ W,
             const float* __restrict__ bias, void* __restrict__ Cv,
             int M, int N, int K,
             const u16* __restrict__ I, const float* __restrict__ sw)
{
  __shared__ __align__(16) u16 As[128*64];
  __shared__ __align__(16) u16 Bs[128*64];
  const int tid  = threadIdx.x;
  const int lane = tid & 63;
  const int wave = tid >> 6;
  const int wr = wave >> 1, wc = wave & 1;
  const int m0 = blockIdx.y * 128, n0 = blockIdx.x * 128;

  f32x4 acc[4][4];
  #pragma unroll
  for (int r=0;r<4;++r)
    #pragma unroll
    for (int c=0;c<4;++c)
      #pragma unroll
      for (int e=0;e<4;++e) acc[r][c][e] = 0.f;

  int srow[4], soff[4];
  #pragma unroll
  for (int j=0;j<4;++j){
    int rr = (wave*4 + j)*8 + (lane>>3);
    srow[j] = rr;
    soff[j] = ((lane & 7) ^ (rr & 7)) * 8;   // pre-swizzled global chunk
  }

  for (int k0 = 0; k0 < K; k0 += 64){
    #pragma unroll
    for (int j=0;j<4;++j){
      gload_lds16(A + (size_t)(m0 + srow[j])*K + k0 + soff[j], As + (wave*4+j)*512);
      gload_lds16(W + (size_t)(n0 + srow[j])*K + k0 + soff[j], Bs + (wave*4+j)*512);
    }
    __syncthreads();
    #pragma unroll
    for (int ks=0; ks<2; ++ks){
      bf16x8 af[4], bfr[4];
      #pragma unroll
      for (int r=0;r<4;++r){
        int row = wr*64 + r*16 + (lane&15);
        int cs  = (ks*4 + (lane>>4)) ^ (row & 7);
        af[r] = *(const bf16x8*)(As + row*64 + cs*8);
      }
      #pragma unroll
      for (int c=0;c<4;++c){
        int row = wc*64 + c*16 + (lane&15);
        int cs  = (ks*4 + (lane>>4)) ^ (row & 7);
        bfr[c] = *(const bf16x8*)(Bs + row*64 + cs*8);
      }
      #pragma unroll
      for (int r=0;r<4;++r)
        #pragma unroll
        for (int c=0;c<4;++c)
          acc[r][c] = __builtin_amdgcn_mfma_f32_16x16x32_bf16(af[r], bfr[c], acc[r][c], 0,0,0);
    }
    __syncthreads();
  }

  float w0 = 0.f;
  if (EPI == 2){
    float s0 = sw[0], s1 = sw[1], s2 = sw[2];
    float mx = fmaxf(s0, fmaxf(s1, s2));
    float e0 = __expf(s0-mx), e1 = __expf(s1-mx), e2 = __expf(s2-mx);
    w0 = e0 / (e0 + e1 + e2);
  }
  u16*   C16 = (u16*)Cv;
  float* C32 = (float*)Cv;
  #pragma unroll
  for (int c=0;c<4;++c){
    int col = n0 + wc*64 + c*16 + (lane&15);
    float bv = bias[col];
    #pragma unroll
    for (int r=0;r<4;++r){
      int rbase = m0 + wr*64 + r*16 + (lane>>4)*4;
      #pragma unroll
      for (int e=0;e<4;++e){
        int row = rbase + e;
        float v = acc[r][c][e] + bv;
        if (EPI == 1) v = v / (1.f + __expf(-v));
        if (EPI == 2){
          v = bf2f(I[(size_t)row*N + col]) + w0 * v;
          C32[(size_t)row*N + col] = v;
        } else {
          C16[(size_t)row*N + col] = f2bf(v);
        }
      }
    }
  }
}

// ---------------- LayerNorm (one wave per token) ----------------
template<int D, int MASK, int OUTF32>
__global__ __launch_bounds__(256, 4)
void ln_k(const u16* __restrict__ H, const float* __restrict__ g,
          const float* __restrict__ beta, const int* __restrict__ st,
          int eid, void* __restrict__ outp, u16* __restrict__ cat, int catOff)
{
  const int tid = threadIdx.x, lane = tid & 63, wave = tid >> 6;
  const int token = blockIdx.x * 4 + wave;
  constexpr int VPT = D / 64;
  float v[VPT];
  const u16* row = H + (size_t)token * D + lane * VPT;
  #pragma unroll
  for (int i=0;i<VPT/2;++i){
    u32 u = ((const u32*)row)[i];
    v[2*i]   = bf2f((u16)(u & 0xFFFFu));
    v[2*i+1] = bf2f((u16)(u >> 16));
  }
  float s = 0.f;
  #pragma unroll
  for (int i=0;i<VPT;++i) s += v[i];
  #pragma unroll
  for (int off=1; off<64; off<<=1) s += __shfl_xor(s, off);
  float mu = s * (1.f / D);
  float q = 0.f;
  #pragma unroll
  for (int i=0;i<VPT;++i){ float d = v[i] - mu; q += d * d; }
  #pragma unroll
  for (int off=1; off<64; off<<=1) q += __shfl_xor(q, off);
  float rs = rsqrtf(q * (1.f / D) + 1e-5f);
  float msk = 1.f;
  if (MASK) msk = (st[token] == eid) ? 1.f : 0.f;
  u16* crow = cat + (size_t)token * 896 + catOff + lane * VPT;
  #pragma unroll
  for (int i=0;i<VPT;++i){
    float gg = g[lane*VPT + i];
    float bb = beta[lane*VPT + i];
    float val = (gg * (v[i] - mu) * rs + bb) * msk;
    if (OUTF32) ((float*)outp)[(size_t)token * D + lane * VPT + i] = val;
    else        ((u16*)outp)[(size_t)token * D + lane * VPT + i] = f2bf(val);
    if (MASK) crow[i] = f2bf(val);
  }
}

// ---------------- flash attention (B=4,S=2048,H=8,Dh=128) ----------------
// v2: Q hoisted to registers (no Qs LDS); Vt chunk-XOR swizzled (T2) to kill
// the 16-way bank conflict on the transpose scatter. LDS 45KB -> 3 blocks/CU.
__global__ __launch_bounds__(256, 3)
void flash_attn(const u16* __restrict__ qkv, u16* __restrict__ o)
{
  __shared__ __align__(16) u16 Ks[64*136];
  __shared__ __align__(16) u16 Vt[128*72];
  __shared__ __align__(16) u16 Ps[4*16*72];
  const int tid = threadIdx.x, lane = tid & 63, wave = tid >> 6;
  const int b = blockIdx.z, h = blockIdx.y, q0 = blockIdx.x * 64;
  const float scale = 0.08838834764831845f;  // 1/sqrt(128)

  // Q fragments in registers: wave's 16 q-rows, all 128 d (4 k-slices of 32)
  bf16x8 qreg[4];
  {
    const u16* qrow = qkv + (size_t)(b*2048 + q0 + wave*16 + (lane&15))*3072
                      + h*128 + (lane>>4)*8;
    #pragma unroll
    for (int kk=0;kk<4;++kk) qreg[kk] = *(const bf16x8*)(qrow + kk*32);
  }

  f32x4 oacc[8];
  #pragma unroll
  for (int f=0;f<8;++f)
    #pragma unroll
    for (int e=0;e<4;++e) oacc[f][e] = 0.f;
  float m_run[4] = {-3e38f,-3e38f,-3e38f,-3e38f};
  float l_run[4] = {0.f,0.f,0.f,0.f};

  for (int kt=0; kt<32; ++kt){
    const int k0 = kt * 64;
    #pragma unroll
    for (int i=0;i<4;++i){
      int id = tid + 256*i;
      int r = id >> 4, c8 = id & 15;
      const size_t rb = (size_t)(b*2048 + k0 + r)*3072 + h*128;
      *(uint4*)(Ks + r*136 + c8*8) = *(const uint4*)(qkv + rb + 1024 + c8*8);
      uint4 tv = *(const uint4*)(qkv + rb + 2048 + c8*8);
      const u16* pv = (const u16*)&tv;
      #pragma unroll
      for (int j=0;j<8;++j){
        int d = c8*8 + j;
        // chunk-XOR swizzle: kv-chunk (r>>3) stored at slot (r>>3)^((d>>3)&7)
        Vt[d*72 + ((((r>>3) ^ (d>>3)) & 7)<<3) + (r&7)] = pv[j];
      }
    }
    __syncthreads();

    f32x4 s[4];
    #pragma unroll
    for (int cb=0;cb<4;++cb)
      #pragma unroll
      for (int e=0;e<4;++e) s[cb][e] = 0.f;
    #pragma unroll
    for (int kk=0;kk<4;++kk){
      #pragma unroll
      for (int cb=0;cb<4;++cb){
        bf16x8 bk = *(const bf16x8*)(Ks + ((lane&15) + 16*cb)*136 + kk*32 + (lane>>4)*8);
        s[cb] = __builtin_amdgcn_mfma_f32_16x16x32_bf16(qreg[kk], bk, s[cb], 0,0,0);
      }
    }

    u16* PsW = Ps + wave*16*72;
    #pragma unroll
    for (int e=0;e<4;++e){
      float t0 = s[0][e]*scale, t1 = s[1][e]*scale, t2 = s[2][e]*scale, t3 = s[3][e]*scale;
      float mx = fmaxf(fmaxf(t0,t1), fmaxf(t2,t3));
      #pragma unroll
      for (int off=1; off<16; off<<=1) mx = fmaxf(mx, __shfl_xor(mx, off));
      float mnew = fmaxf(m_run[e], mx);
      float a = __expf(m_run[e] - mnew);
      m_run[e] = mnew;
      float p0 = __expf(t0-mnew), p1 = __expf(t1-mnew), p2 = __expf(t2-mnew), p3 = __expf(t3-mnew);
      float rsum = p0+p1+p2+p3;
      #pragma unroll
      for (int off=1; off<16; off<<=1) rsum += __shfl_xor(rsum, off);
      l_run[e] = l_run[e]*a + rsum;
      #pragma unroll
      for (int f=0;f<8;++f) oacc[f][e] *= a;
      int prow = (lane>>4)*4 + e;
      PsW[prow*72 +  0 + (lane&15)] = f2bf(p0);
      PsW[prow*72 + 16 + (lane&15)] = f2bf(p1);
      PsW[prow*72 + 32 + (lane&15)] = f2bf(p2);
      PsW[prow*72 + 48 + (lane&15)] = f2bf(p3);
    }

    #pragma unroll
    for (int kk=0;kk<2;++kk){
      bf16x8 pa = *(const bf16x8*)(PsW + (lane&15)*72 + kk*32 + (lane>>4)*8);
      #pragma unroll
      for (int f=0;f<8;++f){
        int drow = (lane&15) + 16*f;
        int chunk = ((kk*4 + (lane>>4)) ^ (drow>>3)) & 7;
        bf16x8 vb = *(const bf16x8*)(Vt + drow*72 + chunk*8);
        oacc[f] = __builtin_amdgcn_mfma_f32_16x16x32_bf16(pa, vb, oacc[f], 0,0,0);
      }
    }
    __syncthreads();
  }

  #pragma unroll
  for (int f=0;f<8;++f)
    #pragma unroll
    for (int e=0;e<4;++e){
      int row = q0 + wave*16 + (lane>>4)*4 + e;
      int col = h*128 + f*16 + (lane&15);
      o[(size_t)(b*2048 + row)*1024 + col] = f2bf(oacc[f][e] / l_run[e]);
    }
}

// ---------------- launch ----------------
extern "C" void kernel_launch(void* const* d_in, const int* in_sizes, int n_in,
                              void* d_out, int out_size, void* d_ws, size_t ws_size,
                              hipStream_t stream)
{
  const float* x         = (const float*)d_in[0];
  const int*   stypes    = (const int*)d_in[1];
  const float* mol_W1    = (const float*)d_in[2];
  const float* mol_b1    = (const float*)d_in[3];
  const float* mol_W2    = (const float*)d_in[4];
  const float* mol_b2    = (const float*)d_in[5];
  const float* mol_g     = (const float*)d_in[6];
  const float* mol_beta  = (const float*)d_in[7];
  const float* path_W1   = (const float*)d_in[8];
  const float* path_b1   = (const float*)d_in[9];
  const float* path_W2   = (const float*)d_in[10];
  const float* path_b2   = (const float*)d_in[11];
  const float* path_g    = (const float*)d_in[12];
  const float* path_beta = (const float*)d_in[13];
  const float* cell_W1   = (const float*)d_in[14];
  const float* cell_b1   = (const float*)d_in[15];
  const float* cell_W2   = (const float*)d_in[16];
  const float* cell_b2   = (const float*)d_in[17];
  const float* cell_g    = (const float*)d_in[18];
  const float* cell_beta = (const float*)d_in[19];
  const float* int_W1    = (const float*)d_in[20];
  const float* int_b1    = (const float*)d_in[21];
  const float* int_W2    = (const float*)d_in[22];
  const float* int_b2    = (const float*)d_in[23];
  const float* int_g     = (const float*)d_in[24];
  const float* int_beta  = (const float*)d_in[25];
  const float* attn_Wqkv = (const float*)d_in[26];
  const float* attn_bqkv = (const float*)d_in[27];
  const float* attn_Wo   = (const float*)d_in[28];
  const float* attn_bo   = (const float*)d_in[29];
  const float* scale_w   = (const float*)d_in[30];

  float* out_final = (float*)d_out;           // [8192,1024] f32
  float* out_mol   = out_final + 8388608;     // [8192,128]  f32
  float* out_path  = out_mol   + 1048576;     // [8192,256]  f32
  float* out_cell  = out_path  + 2097152;     // [8192,512]  f32

  u16* ws    = (u16*)d_ws;
  u16* qkv   = ws;                  // 8192*3072 (early: xb + cat)
  u16* integ = qkv   + 25165824;    // 8192*1024
  u16* S1    = integ + 8388608;     // 8192*1024 scratch
  u16* S2    = S1    + 8388608;     // 8192*1024 scratch
  u16* wb    = S2    + 8388608;     // bf16 weights
  u16* xb    = qkv;                 // [8192,1024] bf16 (dead before qkv GEMM)
  u16* cat   = qkv + 8388608;       // [8192,896] bf16 (dead before qkv GEMM)

  // bf16 weight copies
  u16* molW1b  = wb;                   // 131072
  u16* molW2b  = molW1b  + 131072;     // 16384
  u16* pathW1b = molW2b  + 16384;      // 262144
  u16* pathW2b = pathW1b + 262144;     // 65536
  u16* cellW1b = pathW2b + 65536;      // 524288
  u16* cellW2b = cellW1b + 524288;     // 262144
  u16* intW1b  = cellW2b + 262144;     // 917504
  u16* intW2b  = intW1b  + 917504;     // 1048576
  u16* qkvWb   = intW2b  + 1048576;    // 3145728
  u16* woWb    = qkvWb   + 3145728;    // 1048576

  dim3 blk(256);
  const int M = 8192;
  auto conv = [&](const float* s, u16* d, int n){
    int n8 = n / 8;
    f32_to_bf16<<<(n8 + 255)/256, blk, 0, stream>>>(s, d, n8);
  };

  conv(x,         xb,      8388608);
  conv(mol_W1,    molW1b,  131072);
  conv(mol_W2,    molW2b,  16384);
  conv(path_W1,   pathW1b, 262144);
  conv(path_W2,   pathW2b, 65536);
  conv(cell_W1,   cellW1b, 524288);
  conv(cell_W2,   cellW2b, 262144);
  conv(int_W1,    intW1b,  917504);
  conv(int_W2,    intW2b,  1048576);
  conv(attn_Wqkv, qkvWb,   3145728);
  conv(attn_Wo,   woWb,    1048576);

  // experts (dense over all tokens; masked at LN)
  gemm_bt<1><<<dim3(1,64), blk, 0, stream>>>(xb, molW1b, mol_b1, S1, M, 128, 1024, nullptr, nullptr);
  gemm_bt<0><<<dim3(1,64), blk, 0, stream>>>(S1, molW2b, mol_b2, S2, M, 128, 128,  nullptr, nullptr);
  ln_k<128,1,1><<<2048, blk, 0, stream>>>(S2, mol_g, mol_beta, stypes, 0, out_mol, cat, 0);

  gemm_bt<1><<<dim3(2,64), blk, 0, stream>>>(xb, pathW1b, path_b1, S1, M, 256, 1024, nullptr, nullptr);
  gemm_bt<0><<<dim3(2,64), blk, 0, stream>>>(S1, pathW2b, path_b2, S2, M, 256, 256,  nullptr, nullptr);
  ln_k<256,1,1><<<2048, blk, 0, stream>>>(S2, path_g, path_beta, stypes, 1, out_path, cat, 128);

  gemm_bt<1><<<dim3(4,64), blk, 0, stream>>>(xb, cellW1b, cell_b1, S1, M, 512, 1024, nullptr, nullptr);
  gemm_bt<0><<<dim3(4,64), blk, 0, stream>>>(S1, cellW2b, cell_b2, S2, M, 512, 512,  nullptr, nullptr);
  ln_k<512,1,1><<<2048, blk, 0, stream>>>(S2, cell_g, cell_beta, stypes, 2, out_cell, cat, 384);

  // integration
  gemm_bt<1><<<dim3(8,64), blk, 0, stream>>>(cat, intW1b, int_b1, S1, M, 1024, 896,  nullptr, nullptr);
  gemm_bt<0><<<dim3(8,64), blk, 0, stream>>>(S1,  intW2b, int_b2, S2, M, 1024, 1024, nullptr, nullptr);
  ln_k<1024,0,0><<<2048, blk, 0, stream>>>(S2, int_g, int_beta, nullptr, 0, integ, integ, 0);

  // attention (xb/cat dead from here; qkv region reused)
  gemm_bt<0><<<dim3(24,64), blk, 0, stream>>>(integ, qkvWb, attn_bqkv, qkv, M, 3072, 1024, nullptr, nullptr);
  flash_attn<<<dim3(32,8,4), blk, 0, stream>>>(qkv, S1);

  // final = integ + w0*(o @ Wo^T + bo), f32 out
  gemm_bt<2><<<dim3(8,64), blk, 0, stream>>>(S1, woWb, attn_bo, out_final, M, 1024, 1024, integ, scale_w);
}

// Round 5
// 450.505 us; speedup vs baseline: 1.4781x; 1.2895x over previous
//
#include <hip/hip_runtime.h>
#include <cstdint>
#include <cstddef>

typedef unsigned short u16;
typedef unsigned int u32;
typedef short bf16x8 __attribute__((ext_vector_type(8)));
typedef float f32x4 __attribute__((ext_vector_type(4)));

__device__ __forceinline__ float bf2f(u16 u){
  union { u32 i; float f; } c; c.i = ((u32)u) << 16; return c.f;
}
__device__ __forceinline__ u16 f2bf(float f){
  union { float f; u32 i; } c; c.f = f;
  u32 r = c.i + 0x7FFFu + ((c.i >> 16) & 1u);
  return (u16)(r >> 16);
}
__device__ __forceinline__ void gload_lds16(const void* g, void* l){
  __builtin_amdgcn_global_load_lds(
      (const __attribute__((address_space(1))) u32*)g,
      (__attribute__((address_space(3))) u32*)l, 16, 0, 0);
}

// ---------------- f32 -> bf16 conversion (inputs arrive as float32) --------
__global__ __launch_bounds__(256)
void f32_to_bf16(const float* __restrict__ src, u16* __restrict__ dst, int n8){
  int i = blockIdx.x * 256 + threadIdx.x;
  if (i >= n8) return;
  const float4* s = (const float4*)src + (size_t)i * 2;
  float4 a = s[0], b = s[1];
  u16 o[8] = {f2bf(a.x),f2bf(a.y),f2bf(a.z),f2bf(a.w),
              f2bf(b.x),f2bf(b.y),f2bf(b.z),f2bf(b.w)};
  *(uint4*)(dst + (size_t)i * 8) = *(const uint4*)o;
}

// ---------------- generic GEMM: C = epi(A @ W^T + bias) ----------------
template<int EPI>
__global__ __launch_bounds__(256, 2)
void gemm_bt(const u16* __restrict__ A, const u16* __restrict__ W,
             const float* __restrict__ bias, void* __restrict__ Cv,
             int M, int N, int K,
             const u16* __restrict__ I, const float* __restrict__ sw)
{
  __shared__ __align__(16) u16 As[128*64];
  __shared__ __align__(16) u16 Bs[128*64];
  const int tid  = threadIdx.x;
  const int lane = tid & 63;
  const int wave = tid >> 6;
  const int wr = wave >> 1, wc = wave & 1;
  const int m0 = blockIdx.y * 128, n0 = blockIdx.x * 128;

  f32x4 acc[4][4];
  #pragma unroll
  for (int r=0;r<4;++r)
    #pragma unroll
    for (int c=0;c<4;++c)
      #pragma unroll
      for (int e=0;e<4;++e) acc[r][c][e] = 0.f;

  int srow[4], soff[4];
  #pragma unroll
  for (int j=0;j<4;++j){
    int rr = (wave*4 + j)*8 + (lane>>3);
    srow[j] = rr;
    soff[j] = ((lane & 7) ^ (rr & 7)) * 8;
  }

  for (int k0 = 0; k0 < K; k0 += 64){
    #pragma unroll
    for (int j=0;j<4;++j){
      gload_lds16(A + (size_t)(m0 + srow[j])*K + k0 + soff[j], As + (wave*4+j)*512);
      gload_lds16(W + (size_t)(n0 + srow[j])*K + k0 + soff[j], Bs + (wave*4+j)*512);
    }
    __syncthreads();
    #pragma unroll
    for (int ks=0; ks<2; ++ks){
      bf16x8 af[4], bfr[4];
      #pragma unroll
      for (int r=0;r<4;++r){
        int row = wr*64 + r*16 + (lane&15);
        int cs  = (ks*4 + (lane>>4)) ^ (row & 7);
        af[r] = *(const bf16x8*)(As + row*64 + cs*8);
      }
      #pragma unroll
      for (int c=0;c<4;++c){
        int row = wc*64 + c*16 + (lane&15);
        int cs  = (ks*4 + (lane>>4)) ^ (row & 7);
        bfr[c] = *(const bf16x8*)(Bs + row*64 + cs*8);
      }
      #pragma unroll
      for (int r=0;r<4;++r)
        #pragma unroll
        for (int c=0;c<4;++c)
          acc[r][c] = __builtin_amdgcn_mfma_f32_16x16x32_bf16(af[r], bfr[c], acc[r][c], 0,0,0);
    }
    __syncthreads();
  }

  float w0 = 0.f;
  if (EPI == 2){
    float s0 = sw[0], s1 = sw[1], s2 = sw[2];
    float mx = fmaxf(s0, fmaxf(s1, s2));
    float e0 = __expf(s0-mx), e1 = __expf(s1-mx), e2 = __expf(s2-mx);
    w0 = e0 / (e0 + e1 + e2);
  }
  u16*   C16 = (u16*)Cv;
  float* C32 = (float*)Cv;
  #pragma unroll
  for (int c=0;c<4;++c){
    int col = n0 + wc*64 + c*16 + (lane&15);
    float bv = bias[col];
    #pragma unroll
    for (int r=0;r<4;++r){
      int rbase = m0 + wr*64 + r*16 + (lane>>4)*4;
      #pragma unroll
      for (int e=0;e<4;++e){
        int row = rbase + e;
        float v = acc[r][c][e] + bv;
        if (EPI == 1) v = v / (1.f + __expf(-v));
        if (EPI == 2){
          v = bf2f(I[(size_t)row*N + col]) + w0 * v;
          C32[(size_t)row*N + col] = v;
        } else {
          C16[(size_t)row*N + col] = f2bf(v);
        }
      }
    }
  }
}

// ---------------- LayerNorm (one wave per token) ----------------
template<int D, int MASK, int OUTF32>
__global__ __launch_bounds__(256, 4)
void ln_k(const u16* __restrict__ H, const float* __restrict__ g,
          const float* __restrict__ beta, const int* __restrict__ st,
          int eid, void* __restrict__ outp, u16* __restrict__ cat, int catOff)
{
  const int tid = threadIdx.x, lane = tid & 63, wave = tid >> 6;
  const int token = blockIdx.x * 4 + wave;
  constexpr int VPT = D / 64;
  float v[VPT];
  const u16* row = H + (size_t)token * D + lane * VPT;
  #pragma unroll
  for (int i=0;i<VPT/2;++i){
    u32 u = ((const u32*)row)[i];
    v[2*i]   = bf2f((u16)(u & 0xFFFFu));
    v[2*i+1] = bf2f((u16)(u >> 16));
  }
  float s = 0.f;
  #pragma unroll
  for (int i=0;i<VPT;++i) s += v[i];
  #pragma unroll
  for (int off=1; off<64; off<<=1) s += __shfl_xor(s, off);
  float mu = s * (1.f / D);
  float q = 0.f;
  #pragma unroll
  for (int i=0;i<VPT;++i){ float d = v[i] - mu; q += d * d; }
  #pragma unroll
  for (int off=1; off<64; off<<=1) q += __shfl_xor(q, off);
  float rs = rsqrtf(q * (1.f / D) + 1e-5f);
  float msk = 1.f;
  if (MASK) msk = (st[token] == eid) ? 1.f : 0.f;
  u16* crow = cat + (size_t)token * 896 + catOff + lane * VPT;
  #pragma unroll
  for (int i=0;i<VPT;++i){
    float gg = g[lane*VPT + i];
    float bb = beta[lane*VPT + i];
    float val = (gg * (v[i] - mu) * rs + bb) * msk;
    if (OUTF32) ((float*)outp)[(size_t)token * D + lane * VPT + i] = val;
    else        ((u16*)outp)[(size_t)token * D + lane * VPT + i] = f2bf(val);
    if (MASK) crow[i] = f2bf(val);
  }
}

// ---------------- V transpose: qkv V-part -> vt[b*8+h][d][s] --------------
// 64x64 LDS tiles, XOR swizzle (chunk ^ (row>>3)) so both write (b128) and
// strided read sides are conflict-even.
__global__ __launch_bounds__(256)
void transpose_v(const u16* __restrict__ qkv, u16* __restrict__ vt)
{
  __shared__ __align__(16) u16 T[64*72];
  const int tid = threadIdx.x;
  const int tt = blockIdx.x;      // token tile (0..31)
  const int dt = blockIdx.y;      // d tile (0..1)
  const int bh = blockIdx.z;      // b*8+h
  const int b = bh >> 3, h = bh & 7;
  #pragma unroll
  for (int i=0;i<2;++i){
    int idx = tid + 256*i;
    int r = idx >> 3, c8 = idx & 7;
    const uint4* src = (const uint4*)(qkv + (size_t)(b*2048 + tt*64 + r)*3072
                                      + 2048 + h*128 + dt*64 + c8*8);
    *(uint4*)(T + r*72 + ((c8 ^ (r>>3)) & 7)*8) = *src;
  }
  __syncthreads();
  #pragma unroll
  for (int i=0;i<2;++i){
    int idx = tid + 256*i;
    int dr = idx >> 3, tc = idx & 7;
    u16 tmp[8];
    #pragma unroll
    for (int j=0;j<8;++j){
      int row = tc*8 + j;
      tmp[j] = T[row*72 + (((dr>>3) ^ (row>>3)) & 7)*8 + (dr & 7)];
    }
    *(uint4*)(vt + ((size_t)bh*128 + dt*64 + dr)*2048 + tt*64 + tc*8) = *(const uint4*)tmp;
  }
}

// ---------------- flash attention v3 (B=4,S=2048,H=8,Dh=128) --------------
// Double-buffered async staging (global_load_lds w16, XOR-swizzled K and V^T
// tiles), counted vmcnt(8) pipeline with raw barriers, setprio on MFMA.
__global__ __launch_bounds__(256, 2)
void flash_attn(const u16* __restrict__ qkv, const u16* __restrict__ vt,
                u16* __restrict__ o)
{
  __shared__ __align__(16) u16 Ks[2][8192];   // [64 kv][128 d], row chunks XOR'd
  __shared__ __align__(16) u16 Vs[2][8192];   // [128 d][64 kv], row chunks XOR'd
  __shared__ __align__(16) u16 Ps[4*1152];
  const int tid = threadIdx.x, lane = tid & 63, wave = tid >> 6;
  const int b = blockIdx.z, h = blockIdx.y, q0 = blockIdx.x * 64;
  const float scale = 0.08838834764831845f;  // 1/sqrt(128)

  // Q fragments in registers
  bf16x8 qreg[4];
  {
    const u16* qrow = qkv + (size_t)(b*2048 + q0 + wave*16 + (lane&15))*3072
                      + h*128 + (lane>>4)*8;
    #pragma unroll
    for (int kk=0;kk<4;++kk) qreg[kk] = *(const bf16x8*)(qrow + kk*32);
  }

  // staging source addresses (per-lane, pre-swizzled)
  const u16* ksrc[4]; const u16* vsrc[4]; int cdst[4];
  #pragma unroll
  for (int i=0;i<4;++i){
    int cidx = (wave*4 + i)*64 + lane;
    int krow = cidx >> 4, kcs = cidx & 15;
    int kcsrc = (kcs & 8) | ((kcs & 7) ^ (krow & 7));
    ksrc[i] = qkv + (size_t)(b*2048 + krow)*3072 + h*128 + 1024 + kcsrc*8;
    int vd = cidx >> 3, vcs = cidx & 7;
    vsrc[i] = vt + ((size_t)(b*8 + h)*128 + vd)*2048 + (vcs ^ (vd & 7))*8;
    cdst[i] = cidx * 8;
  }

  auto stage = [&](int buf, int kt){
    #pragma unroll
    for (int i=0;i<4;++i){
      gload_lds16(ksrc[i] + (size_t)kt*196608, &Ks[buf][cdst[i]]);
      gload_lds16(vsrc[i] + kt*64,             &Vs[buf][cdst[i]]);
    }
  };

  f32x4 oacc[8];
  #pragma unroll
  for (int f=0;f<8;++f)
    #pragma unroll
    for (int e=0;e<4;++e) oacc[f][e] = 0.f;
  float m_run[4] = {-3e38f,-3e38f,-3e38f,-3e38f};
  float l_run[4] = {0.f,0.f,0.f,0.f};
  u16* PsW = Ps + wave*1152;

  auto compute = [&](int buf){
    const u16* Kb = Ks[buf];
    const u16* Vb = Vs[buf];
    f32x4 s[4];
    #pragma unroll
    for (int cb=0;cb<4;++cb)
      #pragma unroll
      for (int e=0;e<4;++e) s[cb][e] = 0.f;
    __builtin_amdgcn_s_setprio(1);
    #pragma unroll
    for (int kk=0;kk<4;++kk){
      #pragma unroll
      for (int cb=0;cb<4;++cb){
        int row  = (lane&15) + 16*cb;
        int c    = kk*4 + (lane>>4);
        int slot = (c & 8) | ((c & 7) ^ (row & 7));
        bf16x8 bk = *(const bf16x8*)(Kb + row*128 + slot*8);
        s[cb] = __builtin_amdgcn_mfma_f32_16x16x32_bf16(qreg[kk], bk, s[cb], 0,0,0);
      }
    }
    __builtin_amdgcn_s_setprio(0);

    #pragma unroll
    for (int e=0;e<4;++e){
      float t0 = s[0][e]*scale, t1 = s[1][e]*scale, t2 = s[2][e]*scale, t3 = s[3][e]*scale;
      float mx = fmaxf(fmaxf(t0,t1), fmaxf(t2,t3));
      #pragma unroll
      for (int off=1; off<16; off<<=1) mx = fmaxf(mx, __shfl_xor(mx, off));
      float mnew = fmaxf(m_run[e], mx);
      float a = __expf(m_run[e] - mnew);
      m_run[e] = mnew;
      float p0 = __expf(t0-mnew), p1 = __expf(t1-mnew), p2 = __expf(t2-mnew), p3 = __expf(t3-mnew);
      float rsum = p0+p1+p2+p3;
      #pragma unroll
      for (int off=1; off<16; off<<=1) rsum += __shfl_xor(rsum, off);
      l_run[e] = l_run[e]*a + rsum;
      #pragma unroll
      for (int f=0;f<8;++f) oacc[f][e] *= a;
      int prow = (lane>>4)*4 + e;
      PsW[prow*72 +  0 + (lane&15)] = f2bf(p0);
      PsW[prow*72 + 16 + (lane&15)] = f2bf(p1);
      PsW[prow*72 + 32 + (lane&15)] = f2bf(p2);
      PsW[prow*72 + 48 + (lane&15)] = f2bf(p3);
    }

    __builtin_amdgcn_s_setprio(1);
    #pragma unroll
    for (int kk=0;kk<2;++kk){
      bf16x8 pa = *(const bf16x8*)(PsW + (lane&15)*72 + kk*32 + (lane>>4)*8);
      #pragma unroll
      for (int f=0;f<8;++f){
        int d = f*16 + (lane&15);
        int c = kk*4 + (lane>>4);
        bf16x8 vb = *(const bf16x8*)(Vb + d*64 + (c ^ (d & 7))*8);
        oacc[f] = __builtin_amdgcn_mfma_f32_16x16x32_bf16(pa, vb, oacc[f], 0,0,0);
      }
    }
    __builtin_amdgcn_s_setprio(0);
  };

  stage(0, 0);
  for (int kt=0; kt<31; ++kt){
    stage((kt+1)&1, kt+1);
    asm volatile("s_waitcnt vmcnt(8)" ::: "memory");
    __builtin_amdgcn_s_barrier();
    asm volatile("" ::: "memory");
    compute(kt&1);
    asm volatile("" ::: "memory");
    __builtin_amdgcn_s_barrier();
  }
  asm volatile("s_waitcnt vmcnt(0)" ::: "memory");
  __builtin_amdgcn_s_barrier();
  asm volatile("" ::: "memory");
  compute(1);

  #pragma unroll
  for (int f=0;f<8;++f)
    #pragma unroll
    for (int e=0;e<4;++e){
      int row = q0 + wave*16 + (lane>>4)*4 + e;
      int col = h*128 + f*16 + (lane&15);
      o[(size_t)(b*2048 + row)*1024 + col] = f2bf(oacc[f][e] / l_run[e]);
    }
}

// ---------------- launch ----------------
extern "C" void kernel_launch(void* const* d_in, const int* in_sizes, int n_in,
                              void* d_out, int out_size, void* d_ws, size_t ws_size,
                              hipStream_t stream)
{
  const float* x         = (const float*)d_in[0];
  const int*   stypes    = (const int*)d_in[1];
  const float* mol_W1    = (const float*)d_in[2];
  const float* mol_b1    = (const float*)d_in[3];
  const float* mol_W2    = (const float*)d_in[4];
  const float* mol_b2    = (const float*)d_in[5];
  const float* mol_g     = (const float*)d_in[6];
  const float* mol_beta  = (const float*)d_in[7];
  const float* path_W1   = (const float*)d_in[8];
  const float* path_b1   = (const float*)d_in[9];
  const float* path_W2   = (const float*)d_in[10];
  const float* path_b2   = (const float*)d_in[11];
  const float* path_g    = (const float*)d_in[12];
  const float* path_beta = (const float*)d_in[13];
  const float* cell_W1   = (const float*)d_in[14];
  const float* cell_b1   = (const float*)d_in[15];
  const float* cell_W2   = (const float*)d_in[16];
  const float* cell_b2   = (const float*)d_in[17];
  const float* cell_g    = (const float*)d_in[18];
  const float* cell_beta = (const float*)d_in[19];
  const float* int_W1    = (const float*)d_in[20];
  const float* int_b1    = (const float*)d_in[21];
  const float* int_W2    = (const float*)d_in[22];
  const float* int_b2    = (const float*)d_in[23];
  const float* int_g     = (const float*)d_in[24];
  const float* int_beta  = (const float*)d_in[25];
  const float* attn_Wqkv = (const float*)d_in[26];
  const float* attn_bqkv = (const float*)d_in[27];
  const float* attn_Wo   = (const float*)d_in[28];
  const float* attn_bo   = (const float*)d_in[29];
  const float* scale_w   = (const float*)d_in[30];

  float* out_final = (float*)d_out;           // [8192,1024] f32
  float* out_mol   = out_final + 8388608;     // [8192,128]  f32
  float* out_path  = out_mol   + 1048576;     // [8192,256]  f32
  float* out_cell  = out_path  + 2097152;     // [8192,512]  f32

  u16* ws    = (u16*)d_ws;
  u16* qkv   = ws;                  // 8192*3072 (early: xb + cat)
  u16* integ = qkv   + 25165824;    // 8192*1024
  u16* S1    = integ + 8388608;     // 8192*1024 scratch
  u16* S2    = S1    + 8388608;     // 8192*1024 scratch (later: vt)
  u16* wb    = S2    + 8388608;     // bf16 weights
  u16* xb    = qkv;                 // [8192,1024] bf16 (dead before qkv GEMM)
  u16* cat   = qkv + 8388608;       // [8192,896] bf16 (dead before qkv GEMM)

  u16* molW1b  = wb;
  u16* molW2b  = molW1b  + 131072;
  u16* pathW1b = molW2b  + 16384;
  u16* pathW2b = pathW1b + 262144;
  u16* cellW1b = pathW2b + 65536;
  u16* cellW2b = cellW1b + 524288;
  u16* intW1b  = cellW2b + 262144;
  u16* intW2b  = intW1b  + 917504;
  u16* qkvWb   = intW2b  + 1048576;
  u16* woWb    = qkvWb   + 3145728;

  dim3 blk(256);
  const int M = 8192;
  auto conv = [&](const float* s, u16* d, int n){
    int n8 = n / 8;
    f32_to_bf16<<<(n8 + 255)/256, blk, 0, stream>>>(s, d, n8);
  };

  conv(x,         xb,      8388608);
  conv(mol_W1,    molW1b,  131072);
  conv(mol_W2,    molW2b,  16384);
  conv(path_W1,   pathW1b, 262144);
  conv(path_W2,   pathW2b, 65536);
  conv(cell_W1,   cellW1b, 524288);
  conv(cell_W2,   cellW2b, 262144);
  conv(int_W1,    intW1b,  917504);
  conv(int_W2,    intW2b,  1048576);
  conv(attn_Wqkv, qkvWb,   3145728);
  conv(attn_Wo,   woWb,    1048576);

  // experts (dense over all tokens; masked at LN)
  gemm_bt<1><<<dim3(1,64), blk, 0, stream>>>(xb, molW1b, mol_b1, S1, M, 128, 1024, nullptr, nullptr);
  gemm_bt<0><<<dim3(1,64), blk, 0, stream>>>(S1, molW2b, mol_b2, S2, M, 128, 128,  nullptr, nullptr);
  ln_k<128,1,1><<<2048, blk, 0, stream>>>(S2, mol_g, mol_beta, stypes, 0, out_mol, cat, 0);

  gemm_bt<1><<<dim3(2,64), blk, 0, stream>>>(xb, pathW1b, path_b1, S1, M, 256, 1024, nullptr, nullptr);
  gemm_bt<0><<<dim3(2,64), blk, 0, stream>>>(S1, pathW2b, path_b2, S2, M, 256, 256,  nullptr, nullptr);
  ln_k<256,1,1><<<2048, blk, 0, stream>>>(S2, path_g, path_beta, stypes, 1, out_path, cat, 128);

  gemm_bt<1><<<dim3(4,64), blk, 0, stream>>>(xb, cellW1b, cell_b1, S1, M, 512, 1024, nullptr, nullptr);
  gemm_bt<0><<<dim3(4,64), blk, 0, stream>>>(S1, cellW2b, cell_b2, S2, M, 512, 512,  nullptr, nullptr);
  ln_k<512,1,1><<<2048, blk, 0, stream>>>(S2, cell_g, cell_beta, stypes, 2, out_cell, cat, 384);

  // integration
  gemm_bt<1><<<dim3(8,64), blk, 0, stream>>>(cat, intW1b, int_b1, S1, M, 1024, 896,  nullptr, nullptr);
  gemm_bt<0><<<dim3(8,64), blk, 0, stream>>>(S1,  intW2b, int_b2, S2, M, 1024, 1024, nullptr, nullptr);
  ln_k<1024,0,0><<<2048, blk, 0, stream>>>(S2, int_g, int_beta, nullptr, 0, integ, integ, 0);

  // attention (xb/cat dead; S2 dead -> vt)
  gemm_bt<0><<<dim3(24,64), blk, 0, stream>>>(integ, qkvWb, attn_bqkv, qkv, M, 3072, 1024, nullptr, nullptr);
  transpose_v<<<dim3(32,2,32), blk, 0, stream>>>(qkv, S2);
  flash_attn<<<dim3(32,8,4), blk, 0, stream>>>(qkv, S2, S1);

  // final = integ + w0*(o @ Wo^T + bo), f32 out
  gemm_bt<2><<<dim3(8,64), blk, 0, stream>>>(S1, woWb, attn_bo, out_final, M, 1024, 1024, integ, scale_w);
}